// Round 3
// baseline (2851.304 us; speedup 1.0000x reference)
//
#include <hip/hip_runtime.h>
#include <hip/hip_bf16.h>

#define NLAYERS 12
#define D 1024
#define H 16
#define KVH 4
#define HD 64
#define FF 4096
#define VOCAB 32000
#define SMAX 2048
#define NCHUNK 8
#define CHUNK (SMAX / NCHUNK)   // 256

// ---------------- shared helper: block-wide rms scale (256 threads) ----------------
__device__ __forceinline__ float rms_scale_256(const float* __restrict__ h) {
  float ss = 0.f;
  for (int i = threadIdx.x; i < D; i += 256) { float v = h[i]; ss += v * v; }
#pragma unroll
  for (int off = 32; off; off >>= 1) ss += __shfl_down(ss, off, 64);
  __shared__ float w4[4];
  __shared__ float rn;
  if ((threadIdx.x & 63) == 0) w4[threadIdx.x >> 6] = ss;
  __syncthreads();
  if (threadIdx.x == 0)
    rn = rsqrtf((w4[0] + w4[1] + w4[2] + w4[3]) * (1.f / (float)D) + 1e-6f);
  __syncthreads();
  return rn;
}

// ---------------- embedding ----------------
__global__ void embed_kernel(const float* __restrict__ embedw, const int* __restrict__ ids,
                             float* __restrict__ h) {
  int i = blockIdx.x * blockDim.x + threadIdx.x;
  int tok = ids[0];
  h[i] = embedw[(size_t)tok * D + i];
}

// ---------------- fused rmsnorm + qkv gemv ----------------
// grid 96 blocks: [0,64) q, [64,80) k, [80,96) v. 16 cols x 16 k-slices per block.
__global__ void qkv_rms_kernel(const float* __restrict__ h, const float* __restrict__ win,
                               const float* __restrict__ wq, const float* __restrict__ wk,
                               const float* __restrict__ wv, float* __restrict__ qkvb) {
  __shared__ float xs[D];
  float r = rms_scale_256(h);
  for (int i = threadIdx.x; i < D; i += 256) xs[i] = h[i] * r * win[i];
  __syncthreads();
  const int COLS = 16, SLICES = 16;
  int bid = blockIdx.x;
  const float* W; int N; int outoff; int colbase;
  if (bid < 64)      { W = wq; N = 1024; outoff = 0;    colbase = bid * COLS; }
  else if (bid < 80) { W = wk; N = 256;  outoff = 1024; colbase = (bid - 64) * COLS; }
  else               { W = wv; N = 256;  outoff = 1280; colbase = (bid - 80) * COLS; }
  int c = threadIdx.x & (COLS - 1);
  int s = threadIdx.x / COLS;
  int j = colbase + c;
  float acc = 0.f;
  for (int k = s; k < D; k += SLICES) acc += xs[k] * W[(size_t)k * N + j];
  __shared__ float red[SLICES][COLS];
  red[s][c] = acc;
  __syncthreads();
  if (s == 0) {
    float sum = 0.f;
#pragma unroll
    for (int i = 0; i < SLICES; i++) sum += red[i][c];
    qkvb[outoff + j] = sum;
  }
}

// ---------------- generic gemv, optional residual (used for wo) ----------------
template <int COLS>
__global__ void gemv_kernel(const float* __restrict__ W, const float* __restrict__ x,
                            float* y, const float* res, int K, int N) {
  const int SLICES = 256 / COLS;
  int c = threadIdx.x & (COLS - 1);
  int s = threadIdx.x / COLS;
  int j = blockIdx.x * COLS + c;
  float acc = 0.f;
  for (int k = s; k < K; k += SLICES) acc += x[k] * W[(size_t)k * N + j];
  __shared__ float red[SLICES][COLS];
  red[s][c] = acc;
  __syncthreads();
  if (s == 0) {
    float sum = 0.f;
#pragma unroll
    for (int i = 0; i < SLICES; i++) sum += red[i][c];
    if (res) sum += res[j];
    y[j] = sum;
  }
}

// ---------------- fused rmsnorm + gate/up gemv + SwiGLU epilogue ----------------
__global__ void gateup_rms_kernel(const float* __restrict__ h, const float* __restrict__ wpost,
                                  const float* __restrict__ Wg, const float* __restrict__ Wu,
                                  float* __restrict__ ff) {
  __shared__ float xs[D];
  float r = rms_scale_256(h);
  for (int i = threadIdx.x; i < D; i += 256) xs[i] = h[i] * r * wpost[i];
  __syncthreads();
  const int COLS = 16, SLICES = 16;
  int c = threadIdx.x & (COLS - 1);
  int s = threadIdx.x >> 4;
  int j = blockIdx.x * COLS + c;
  float ag = 0.f, au = 0.f;
  for (int k = s; k < D; k += SLICES) {
    float xv = xs[k];
    size_t idx = (size_t)k * FF + j;
    ag += xv * Wg[idx];
    au += xv * Wu[idx];
  }
  __shared__ float rg[SLICES][COLS], ru[SLICES][COLS];
  rg[s][c] = ag; ru[s][c] = au;
  __syncthreads();
  if (s == 0) {
    float g = 0.f, u = 0.f;
#pragma unroll
    for (int i = 0; i < SLICES; i++) { g += rg[i][c]; u += ru[i][c]; }
    ff[j] = (g / (1.f + __expf(-g))) * u;  // silu(g)*u
  }
}

// ---------------- down proj stage 1: split-K float4 partial gemv ----------------
// grid (D/64=16, 8): block (bx,bz) covers cols bx*64..+63 (16 lanes x float4),
// K-range [bz*512, bz*512+512), 16 sub-slices.
__global__ void down_s1_kernel(const float* __restrict__ W, const float* __restrict__ x,
                               float* __restrict__ part) {
  int c = threadIdx.x & 15;
  int s = threadIdx.x >> 4;
  int jbase = blockIdx.x * 64 + c * 4;
  int k0 = blockIdx.y * 512;
  float4 acc = make_float4(0.f, 0.f, 0.f, 0.f);
  for (int k = k0 + s; k < k0 + 512; k += 16) {
    float xv = x[k];
    const float4 w4 = *(const float4*)(W + (size_t)k * D + jbase);
    acc.x += xv * w4.x; acc.y += xv * w4.y; acc.z += xv * w4.z; acc.w += xv * w4.w;
  }
  __shared__ float4 red[16][16];
  red[s][c] = acc;
  __syncthreads();
  if (s == 0) {
    float4 sum = make_float4(0.f, 0.f, 0.f, 0.f);
#pragma unroll
    for (int i = 0; i < 16; i++) {
      float4 t = red[i][c];
      sum.x += t.x; sum.y += t.y; sum.z += t.z; sum.w += t.w;
    }
    *(float4*)(part + (size_t)blockIdx.y * D + jbase) = sum;
  }
}

// ---------------- down proj stage 2: reduce partials + residual (in place on h) ----------------
__global__ void down_s2_kernel(const float* __restrict__ part, float* h) {
  int j = blockIdx.x * 256 + threadIdx.x;
  float sum = h[j];
#pragma unroll
  for (int z = 0; z < 8; z++) sum += part[(size_t)z * D + j];
  h[j] = sum;
}

// ---------------- attention stage 1: per (q-head, S-chunk) online softmax ----------------
__global__ void attn1_kernel(const float* __restrict__ qkvb, const float* __restrict__ kc,
                             const float* __restrict__ vc, const int* __restrict__ clen,
                             float* __restrict__ pm, float* __restrict__ pl,
                             float* __restrict__ po) {
  int hq = blockIdx.x;
  int chunk = blockIdx.y;
  int g = hq >> 2;               // kv head = hq / (H/KVH)
  int lane = threadIdx.x & 63;
  int wave = threadIdx.x >> 6;
  int pos = clen[0];
  int d = lane;
  float f = (float)(d & 31) * (1.f / 32.f);
  float inv_freq = powf(10000.f, -f);
  float ang = (float)pos * inv_freq;
  float cs = cosf(ang), sn = sinf(ang);
  float qa = qkvb[hq * 64 + d];
  float qb = qkvb[hq * 64 + (d ^ 32)];
  float q = qa * cs + ((d < 32) ? -qb : qb) * sn;
  float ka = qkvb[1024 + g * 64 + d];
  float kb = qkvb[1024 + g * 64 + (d ^ 32)];
  float knew = ka * cs + ((d < 32) ? -kb : kb) * sn;
  float vnew = qkvb[1280 + g * 64 + d];
  const float* Kb = kc + (size_t)g * SMAX * 64;
  const float* Vb = vc + (size_t)g * SMAX * 64;
  float m = -1e30f, lsum = 0.f, o = 0.f;
  int j0 = chunk * CHUNK;
  int jend = j0 + CHUNK;
  for (int j = j0 + wave; j < jend; j += 4) {
    if (j > pos) break;  // causal: only j <= pos valid (wave-uniform)
    float kvv = (j == pos) ? knew : Kb[(size_t)j * 64 + d];
    float p = q * kvv;
#pragma unroll
    for (int off = 32; off; off >>= 1) p += __shfl_down(p, off, 64);
    p = __shfl(p, 0, 64) * 0.125f;  // scale = 1/sqrt(64)
    float vv = (j == pos) ? vnew : Vb[(size_t)j * 64 + d];
    float mn = fmaxf(m, p);
    float a = __expf(m - mn);
    float w = __expf(p - mn);
    lsum = lsum * a + w;
    o = o * a + w * vv;
    m = mn;
  }
  __shared__ float sm[4], sl[4], so[4][64];
  if (lane == 0) { sm[wave] = m; sl[wave] = lsum; }
  so[wave][lane] = o;
  __syncthreads();
  if (wave == 0) {
    float M = fmaxf(fmaxf(sm[0], sm[1]), fmaxf(sm[2], sm[3]));
    float L = 0.f, O = 0.f;
#pragma unroll
    for (int w2 = 0; w2 < 4; w2++) {
      float sc = (sm[w2] <= -1e29f) ? 0.f : __expf(sm[w2] - M);
      L += sl[w2] * sc;
      O += so[w2][lane] * sc;
    }
    int idx = hq * NCHUNK + chunk;
    if (lane == 0) { pm[idx] = M; pl[idx] = L; }
    po[idx * 64 + lane] = O;
  }
}

// ---------------- attention stage 2: combine chunks ----------------
__global__ void attn2_kernel(const float* __restrict__ pm, const float* __restrict__ pl,
                             const float* __restrict__ po, float* __restrict__ aout) {
  int hq = blockIdx.x;
  int lane = threadIdx.x;  // 64
  float M = -1e30f;
  for (int c = 0; c < NCHUNK; c++) M = fmaxf(M, pm[hq * NCHUNK + c]);
  float L = 0.f, O = 0.f;
  for (int c = 0; c < NCHUNK; c++) {
    float mc = pm[hq * NCHUNK + c];
    float sc = (mc <= -1e29f) ? 0.f : __expf(mc - M);
    L += pl[hq * NCHUNK + c] * sc;
    O += po[(hq * NCHUNK + c) * 64 + lane] * sc;
  }
  aout[hq * 64 + lane] = O / L;
}

// ---------------- fused final rmsnorm + lm_head gemv ----------------
__global__ void lmhead_rms_kernel(const float* __restrict__ h, const float* __restrict__ fln,
                                  const float* __restrict__ W, float* __restrict__ out) {
  __shared__ float xs[D];
  float r = rms_scale_256(h);
  for (int i = threadIdx.x; i < D; i += 256) xs[i] = h[i] * r * fln[i];
  __syncthreads();
  const int COLS = 16, SLICES = 16;
  int c = threadIdx.x & (COLS - 1);
  int s = threadIdx.x >> 4;
  int j = blockIdx.x * COLS + c;
  float acc = 0.f;
  for (int k = s; k < D; k += SLICES) acc += xs[k] * W[(size_t)k * VOCAB + j];
  __shared__ float red[SLICES][COLS];
  red[s][c] = acc;
  __syncthreads();
  if (s == 0) {
    float sum = 0.f;
#pragma unroll
    for (int i = 0; i < SLICES; i++) sum += red[i][c];
    out[j] = sum;
  }
}

extern "C" void kernel_launch(void* const* d_in, const int* in_sizes, int n_in,
                              void* d_out, int out_size, void* d_ws, size_t ws_size,
                              hipStream_t stream) {
  const int*   ids     = (const int*)  d_in[0];
  const float* embedw  = (const float*)d_in[1];
  const float* w_in_ln = (const float*)d_in[2];
  const float* wq      = (const float*)d_in[3];
  const float* wk      = (const float*)d_in[4];
  const float* wv      = (const float*)d_in[5];
  const float* wo      = (const float*)d_in[6];
  const float* w_post  = (const float*)d_in[7];
  const float* wg      = (const float*)d_in[8];
  const float* wu      = (const float*)d_in[9];
  const float* wd      = (const float*)d_in[10];
  const float* fln     = (const float*)d_in[11];
  const float* lmh     = (const float*)d_in[12];
  const float* kc      = (const float*)d_in[13];
  const float* vc      = (const float*)d_in[14];
  const int*   clen    = (const int*)  d_in[15];
  float* out = (float*)d_out;
  float* ws  = (float*)d_ws;

  // workspace layout (floats)
  float* h     = ws;            // 1024
  float* qkvb  = ws + 1024;     // 1536 (q 1024 | k 256 | v 256)
  float* pm    = ws + 2560;     // 128
  float* pl    = ws + 2688;     // 128
  float* po    = ws + 2816;     // 8192
  float* aout  = ws + 11008;    // 1024
  float* ff    = ws + 12032;    // 4096
  float* dpart = ws + 16128;    // 8192 (8 x 1024)

  embed_kernel<<<4, 256, 0, stream>>>(embedw, ids, h);
  for (int l = 0; l < NLAYERS; l++) {
    const float* wq_l = wq + (size_t)l * D * (H * HD);
    const float* wk_l = wk + (size_t)l * D * (KVH * HD);
    const float* wv_l = wv + (size_t)l * D * (KVH * HD);
    const float* wo_l = wo + (size_t)l * (H * HD) * D;
    const float* wg_l = wg + (size_t)l * D * FF;
    const float* wu_l = wu + (size_t)l * D * FF;
    const float* wd_l = wd + (size_t)l * FF * D;
    const float* kcl  = kc + (size_t)l * KVH * SMAX * HD;
    const float* vcl  = vc + (size_t)l * KVH * SMAX * HD;

    qkv_rms_kernel<<<96, 256, 0, stream>>>(h, w_in_ln + (size_t)l * D,
                                           wq_l, wk_l, wv_l, qkvb);
    attn1_kernel<<<dim3(H, NCHUNK), 256, 0, stream>>>(qkvb, kcl, vcl, clen, pm, pl, po);
    attn2_kernel<<<H, 64, 0, stream>>>(pm, pl, po, aout);
    gemv_kernel<16><<<D / 16, 256, 0, stream>>>(wo_l, aout, h, h, D, D);   // h += attn @ wo
    gateup_rms_kernel<<<FF / 16, 256, 0, stream>>>(h, w_post + (size_t)l * D,
                                                   wg_l, wu_l, ff);
    down_s1_kernel<<<dim3(D / 64, 8), 256, 0, stream>>>(wd_l, ff, dpart);
    down_s2_kernel<<<D / 256, 256, 0, stream>>>(dpart, h);                 // h += ff @ wd
  }
  lmhead_rms_kernel<<<VOCAB / 16, 256, 0, stream>>>(h, fln, lmh, out);
}